// Round 13
// baseline (325.683 us; speedup 1.0000x reference)
//
#include <hip/hip_runtime.h>

#define NNODES 50000
#define NEDGES 800000
#define NF 96
#define NF4 24              // float4 per f32 row
#define NBW 4               // nodes per wave (fused): 12500 waves total
#define WPB 4               // waves per block (256 threads)
#define ACC_STRIDE 97       // Acc row stride (floats)
#define NPW 16              // nodes per wave (node MLP)
#define TSTRIDE 100         // h1 transpose tile stride (floats, 16B-aligned)

typedef short bf16x8 __attribute__((ext_vector_type(8)));
typedef float f32x4 __attribute__((ext_vector_type(4)));

__device__ inline unsigned pk_bf16(float a, float b) {
    union { __bf16 h[2]; unsigned u; } q;
    q.h[0] = (__bf16)a; q.h[1] = (__bf16)b;
    return q.u;
}
__device__ inline unsigned short bf16_1(float a) {
    union { __bf16 h; unsigned short u; } q;
    q.h = (__bf16)a;
    return q.u;
}
__device__ inline bf16x8 cvt8(float4 a, float4 b) {
    union { unsigned u[4]; bf16x8 v; } q;
    q.u[0] = pk_bf16(a.x, a.y); q.u[1] = pk_bf16(a.z, a.w);
    q.u[2] = pk_bf16(b.x, b.y); q.u[3] = pk_bf16(b.z, b.w);
    return q.v;
}
__device__ inline int imin(int a, int b) { return a < b ? a : b; }

// ---------------------------------------------------------------------------
// prep: blocks 0/1/2 pack We/W1/W2 into MFMA B-fragment order (bf16);
// remaining blocks do the dst histogram.
// ---------------------------------------------------------------------------
__global__ __launch_bounds__(256) void prep_hist(
    const float* __restrict__ We, const float* __restrict__ W1,
    const float* __restrict__ W2, unsigned short* __restrict__ Wep,
    unsigned short* __restrict__ W1p, unsigned short* __restrict__ W2p,
    const int* __restrict__ ei, int* __restrict__ deg) {
    int b = blockIdx.x;
    if (b < 3) {
        const float* S = (b == 0) ? We : (b == 1) ? W1 : W2;
        unsigned short* D = (b == 0) ? Wep : (b == 1) ? W1p : W2p;
        for (int i = threadIdx.x; i < 18 * 64 * 8; i += blockDim.x) {
            int f = i >> 9, rem = i & 511;
            int l = rem >> 3, j = rem & 7;
            int ot = f / 3, kb = f % 3;
            int o = ot * 16 + (l & 15);
            int k = kb * 32 + ((l >> 4) << 3) + j;
            D[i] = bf16_1(S[o * NF + k]);
        }
    } else {
        int e = (b - 3) * 256 + threadIdx.x;
        if (e < NEDGES) atomicAdd(&deg[ei[NEDGES + e]], 1);
    }
}

// ---------------------------------------------------------------------------
// 2-kernel scan (partial sums; write does local scan of partials) + fill
// ---------------------------------------------------------------------------
#define SCAN_BLOCKS 196  // ceil(50000 / 256)

__global__ __launch_bounds__(256) void scan_partial(const int* __restrict__ deg,
                                                    int* __restrict__ bsum) {
    __shared__ int red[256];
    int t = threadIdx.x;
    int i = blockIdx.x * 256 + t;
    red[t] = (i < NNODES) ? deg[i] : 0;
    __syncthreads();
    for (int off = 128; off; off >>= 1) {
        if (t < off) red[t] += red[t + off];
        __syncthreads();
    }
    if (t == 0) bsum[blockIdx.x] = red[0];
}

__global__ __launch_bounds__(256) void scan_write(const int* __restrict__ deg,
                                                  const int* __restrict__ bsum,
                                                  int* __restrict__ start,
                                                  int* __restrict__ cursor) {
    __shared__ int sb[256];
    __shared__ int s[256];
    int t = threadIdx.x;
    // local scan of the 196 block partials -> this block's exclusive base
    sb[t] = (t < SCAN_BLOCKS) ? bsum[t] : 0;
    __syncthreads();
    for (int off = 1; off < 256; off <<= 1) {
        int v = (t >= off) ? sb[t - off] : 0;
        __syncthreads();
        sb[t] += v;
        __syncthreads();
    }
    int bbase = (blockIdx.x == 0) ? 0 : sb[blockIdx.x - 1];

    int i = blockIdx.x * 256 + t;
    int d = (i < NNODES) ? deg[i] : 0;
    s[t] = d;
    __syncthreads();
    for (int off = 1; off < 256; off <<= 1) {
        int v = (t >= off) ? s[t - off] : 0;
        __syncthreads();
        s[t] += v;
        __syncthreads();
    }
    int excl = ((t == 0) ? 0 : s[t - 1]) + bbase;
    if (i < NNODES) {
        start[i] = excl;
        cursor[i] = excl;
        if (i == NNODES - 1) start[NNODES] = excl + d;
    }
}

// fill: eidx[p] = edge id; ss[p] = (src, dst) packed
__global__ void fill_kernel(const int* __restrict__ ei, int* __restrict__ cursor,
                            int* __restrict__ eidx, int2* __restrict__ ss) {
    int e = blockIdx.x * blockDim.x + threadIdx.x;
    if (e < NEDGES) {
        int d = ei[NEDGES + e];
        int p = atomicAdd(&cursor[d], 1);
        eidx[p] = e;
        ss[p] = make_int2(ei[e], d);
    }
}

// ---------------------------------------------------------------------------
// Wave-autonomous fused edge-GEMM + segment-sum.
// R13: x2-unrolled pipeline with static A/B buffer roles:
//   attr 2-deep (issue tile tt+2 while computing tt, ~600cy cover),
//   xe 1-deep with NO rotation movs (alternating xeA/xeB),
//   ss/ev cheap int rotation. Tail = padded even tile count (masked).
// ---------------------------------------------------------------------------
__global__ __launch_bounds__(256) void fused_edge_aggr(
    const float* __restrict__ attr, const int* __restrict__ eidx,
    const int2* __restrict__ ss_g, const int* __restrict__ start,
    const float* __restrict__ x, const unsigned short* __restrict__ Wpack,
    const float* __restrict__ be, const float* __restrict__ epsp,
    float* __restrict__ h) {
    __shared__ short Wlds[18 * 64 * 8];             // 18,432 B
    __shared__ float Acc[WPB][NBW][ACC_STRIDE];     //  6,208 B

    const int t = threadIdx.x;
    {
        const uint4* wsrc = reinterpret_cast<const uint4*>(Wpack);
        uint4* wdst = reinterpret_cast<uint4*>(Wlds);
        for (int i = t; i < 18 * 64; i += 256) wdst[i] = wsrc[i];
        float* accf = &Acc[0][0][0];
        for (int i = t; i < WPB * NBW * ACC_STRIDE; i += 256) accf[i] = 0.f;
    }
    __syncthreads();

    const int w = t >> 6;
    const int lane = t & 63;
    const int l15 = lane & 15, l4 = lane >> 4;
    const int n0w = (blockIdx.x * WPB + w) * NBW;
    if (n0w >= NNODES) return;
    const int s0 = start[n0w], s1 = start[n0w + NBW];
    float* AccW = &Acc[w][0][0];

    float bias[6];
#pragma unroll
    for (int ot = 0; ot < 6; ++ot) bias[ot] = be[ot * 16 + l15];

    const float4* a4 = reinterpret_cast<const float4*>(attr);
    const int nt = (s1 - s0 + 15) >> 4;

    if (nt > 0) {
        const int smax = s1 - 1;

        // ---- prologue ----
        float4 aA[6], aB[6];
        float xeA[4][6], xeB[4][6];
        int2 ss_cur[4], ss_nxt[4];
        int ev_n2;
        {
            int evA = eidx[imin(s0 + l15, smax)];
            const float4* ar = a4 + (size_t)evA * NF4 + l4 * 2;
            aA[0] = ar[0];  aA[1] = ar[1];
            aA[2] = ar[8];  aA[3] = ar[9];
            aA[4] = ar[16]; aA[5] = ar[17];
            int evB = eidx[imin(s0 + 16 + l15, smax)];
            const float4* br = a4 + (size_t)evB * NF4 + l4 * 2;
            aB[0] = br[0];  aB[1] = br[1];
            aB[2] = br[8];  aB[3] = br[9];
            aB[4] = br[16]; aB[5] = br[17];
            ev_n2 = eidx[imin(s0 + 32 + l15, smax)];
#pragma unroll
            for (int r = 0; r < 4; ++r) {
                ss_cur[r] = ss_g[imin(s0 + l4 * 4 + r, smax)];
                ss_nxt[r] = ss_g[imin(s0 + 16 + l4 * 4 + r, smax)];
            }
#pragma unroll
            for (int r = 0; r < 4; ++r) {
                const float* xr = x + (size_t)ss_cur[r].x * NF + l15;
#pragma unroll
                for (int ot = 0; ot < 6; ++ot) xeA[r][ot] = xr[ot * 16];
            }
        }

        // one half-iteration body; AIN = consumed attr buf, AOUT = refilled buf,
        // XIN = consumed xe buf, XOUT = xe buf being issued (tile tile_c+1)
#define FUSED_BODY(tile_c, AIN, AOUT, XIN, XOUT)                               \
        {                                                                      \
            const int base = s0 + 16 * (tile_c);                               \
            bf16x8 af[3];                                                      \
            af[0] = cvt8(AIN[0], AIN[1]);                                      \
            af[1] = cvt8(AIN[2], AIN[3]);                                      \
            af[2] = cvt8(AIN[4], AIN[5]);                                      \
            { /* issue attr for tile_c+2 into AOUT */                          \
                const float4* ar = a4 + (size_t)ev_n2 * NF4 + l4 * 2;          \
                AOUT[0] = ar[0];  AOUT[1] = ar[1];                             \
                AOUT[2] = ar[8];  AOUT[3] = ar[9];                             \
                AOUT[4] = ar[16]; AOUT[5] = ar[17];                            \
            }                                                                  \
            ev_n2 = eidx[imin(base + 48 + l15, smax)];                         \
            int m[4];                                                          \
            _Pragma("unroll")                                                  \
            for (int r = 0; r < 4; ++r)                                        \
                m[r] = ((base + l4 * 4 + r) < s1) ? (ss_cur[r].y - n0w) : -1;  \
            _Pragma("unroll")                                                  \
            for (int r = 0; r < 4; ++r) { /* issue xe tile_c+1 from ss_nxt */  \
                const float* xr = x + (size_t)ss_nxt[r].x * NF + l15;          \
                _Pragma("unroll")                                              \
                for (int ot = 0; ot < 6; ++ot) XOUT[r][ot] = xr[ot * 16];      \
            }                                                                  \
            _Pragma("unroll")                                                  \
            for (int r = 0; r < 4; ++r) ss_cur[r] = ss_nxt[r];                 \
            _Pragma("unroll")                                                  \
            for (int r = 0; r < 4; ++r)                                        \
                ss_nxt[r] = ss_g[imin(base + 32 + l4 * 4 + r, smax)];          \
            f32x4 acc[6];                                                      \
            _Pragma("unroll")                                                  \
            for (int ot = 0; ot < 6; ++ot) {                                   \
                f32x4 c = {bias[ot], bias[ot], bias[ot], bias[ot]};            \
                _Pragma("unroll")                                              \
                for (int kb = 0; kb < 3; ++kb) {                               \
                    bf16x8 bf = *reinterpret_cast<const bf16x8*>(              \
                        &Wlds[((ot * 3 + kb) * 64 + lane) * 8]);               \
                    c = __builtin_amdgcn_mfma_f32_16x16x32_bf16(af[kb], bf, c, \
                                                                0, 0, 0);      \
                }                                                              \
                acc[ot] = c;                                                   \
            }                                                                  \
            const bool c1 = (m[1] == m[0]);                                    \
            const bool c2 = (m[2] == m[1]);                                    \
            const bool c3 = (m[3] == m[2]);                                    \
            _Pragma("unroll")                                                  \
            for (int ot = 0; ot < 6; ++ot) {                                   \
                const int o = ot * 16 + l15;                                   \
                float v0 = fmaxf(acc[ot][0] + XIN[0][ot], 0.f);                \
                float v1 = fmaxf(acc[ot][1] + XIN[1][ot], 0.f);                \
                float v2 = fmaxf(acc[ot][2] + XIN[2][ot], 0.f);                \
                float v3 = fmaxf(acc[ot][3] + XIN[3][ot], 0.f);                \
                float run = v0;                                                \
                if (!c1) {                                                     \
                    if (m[0] >= 0) atomicAdd(&AccW[m[0] * ACC_STRIDE + o], run); \
                    run = 0.f;                                                 \
                }                                                              \
                run += v1;                                                     \
                if (!c2) {                                                     \
                    if (m[1] >= 0) atomicAdd(&AccW[m[1] * ACC_STRIDE + o], run); \
                    run = 0.f;                                                 \
                }                                                              \
                run += v2;                                                     \
                if (!c3) {                                                     \
                    if (m[2] >= 0) atomicAdd(&AccW[m[2] * ACC_STRIDE + o], run); \
                    run = 0.f;                                                 \
                }                                                              \
                run += v3;                                                     \
                if (m[3] >= 0) atomicAdd(&AccW[m[3] * ACC_STRIDE + o], run);   \
            }                                                                  \
        }

        for (int tt = 0; tt < nt; tt += 2) {
            FUSED_BODY(tt,     aA, aA, xeA, xeB)   // even: consume A, refill A
            FUSED_BODY(tt + 1, aB, aB, xeB, xeA)   // odd:  consume B, refill B
        }
#undef FUSED_BODY
    }

    // ---- drain this wave's ds_adds, then write h (wave-private) ----
    asm volatile("s_waitcnt lgkmcnt(0)" ::: "memory");
    __builtin_amdgcn_sched_barrier(0);
    const float ep = 1.0f + *epsp;
#pragma unroll
    for (int i = 0; i < NBW * NF / 64; ++i) {  // 6
        int item = lane + 64 * i;
        int n = item / NF, f = item % NF;
        float a = AccW[n * ACC_STRIDE + f];
        size_t g = (size_t)(n0w + n) * NF + f;
        h[g] = fmaf(ep, x[g], a);
    }
}

// ---------------------------------------------------------------------------
// Node MLP via bf16 MFMA. Wave owns NPW=16 nodes (contiguous, dense rows).
// ---------------------------------------------------------------------------
__global__ __launch_bounds__(256) void node_mfma(
    const float* __restrict__ h, const unsigned short* __restrict__ W1p,
    const float* __restrict__ b1, const unsigned short* __restrict__ W2p,
    const float* __restrict__ b2, float* __restrict__ out) {
    __shared__ short W1lds[18 * 64 * 8];          // 18,432 B
    __shared__ short W2lds[18 * 64 * 8];          // 18,432 B
    __shared__ float T[4][NPW][TSTRIDE];          // 25,600 B

    const int t = threadIdx.x;
    {
        const uint4* s1v = reinterpret_cast<const uint4*>(W1p);
        const uint4* s2v = reinterpret_cast<const uint4*>(W2p);
        uint4* d1 = reinterpret_cast<uint4*>(W1lds);
        uint4* d2 = reinterpret_cast<uint4*>(W2lds);
        for (int i = t; i < 18 * 64; i += 256) { d1[i] = s1v[i]; d2[i] = s2v[i]; }
    }
    __syncthreads();

    const int w = t >> 6;
    const int lane = t & 63;
    const int l15 = lane & 15, l4 = lane >> 4;
    const int n0 = (blockIdx.x * 4 + w) * NPW;
    if (n0 >= NNODES) return;

    const float4* hrow = reinterpret_cast<const float4*>(h + (size_t)(n0 + l15) * NF);
    bf16x8 af[3];
#pragma unroll
    for (int kb = 0; kb < 3; ++kb)
        af[kb] = cvt8(hrow[kb * 8 + l4 * 2], hrow[kb * 8 + l4 * 2 + 1]);

    float* Tw = &T[w][0][0];
#pragma unroll
    for (int ot = 0; ot < 6; ++ot) {
        float b = b1[ot * 16 + l15];
        f32x4 c = {b, b, b, b};
#pragma unroll
        for (int kb = 0; kb < 3; ++kb) {
            bf16x8 bf = *reinterpret_cast<const bf16x8*>(
                &W1lds[((ot * 3 + kb) * 64 + lane) * 8]);
            c = __builtin_amdgcn_mfma_f32_16x16x32_bf16(af[kb], bf, c, 0, 0, 0);
        }
#pragma unroll
        for (int r = 0; r < 4; ++r)
            Tw[(l4 * 4 + r) * TSTRIDE + ot * 16 + l15] = fmaxf(c[r], 0.f);
    }

    asm volatile("s_waitcnt lgkmcnt(0)" ::: "memory");
    __builtin_amdgcn_sched_barrier(0);

    bf16x8 af2[3];
#pragma unroll
    for (int kb = 0; kb < 3; ++kb) {
        const float4* tr = reinterpret_cast<const float4*>(
            &Tw[l15 * TSTRIDE + kb * 32 + l4 * 8]);
        af2[kb] = cvt8(tr[0], tr[1]);
    }
#pragma unroll
    for (int ot = 0; ot < 6; ++ot) {
        float b = b2[ot * 16 + l15];
        f32x4 c = {b, b, b, b};
#pragma unroll
        for (int kb = 0; kb < 3; ++kb) {
            bf16x8 bf = *reinterpret_cast<const bf16x8*>(
                &W2lds[((ot * 3 + kb) * 64 + lane) * 8]);
            c = __builtin_amdgcn_mfma_f32_16x16x32_bf16(af2[kb], bf, c, 0, 0, 0);
        }
#pragma unroll
        for (int r = 0; r < 4; ++r)
            out[(size_t)(n0 + l4 * 4 + r) * NF + ot * 16 + l15] = c[r];
    }
}

// ---------------------------------------------------------------------------
extern "C" void kernel_launch(void* const* d_in, const int* in_sizes, int n_in,
                              void* d_out, int out_size, void* d_ws, size_t ws_size,
                              hipStream_t stream) {
    const float* x   = (const float*)d_in[0];
    const int*   ei  = (const int*)d_in[1];
    const float* ea  = (const float*)d_in[2];
    const float* We  = (const float*)d_in[3];
    const float* be  = (const float*)d_in[4];
    const float* eps = (const float*)d_in[5];
    const float* W1  = (const float*)d_in[6];
    const float* b1  = (const float*)d_in[7];
    const float* W2  = (const float*)d_in[8];
    const float* b2  = (const float*)d_in[9];
    float* out = (float*)d_out;

    // ws layout
    float* h    = (float*)d_ws;                          // 50000*96 f (19.2 MB)
    unsigned short* Wep = (unsigned short*)(h + (size_t)NNODES * NF);  // 9216
    unsigned short* W1p = Wep + 18 * 64 * 8;             // 9216
    unsigned short* W2p = W1p + 18 * 64 * 8;             // 9216
    int* deg    = (int*)(W2p + 18 * 64 * 8);             // 50000
    int* start  = deg + NNODES;                          // 50001
    int* cursor = start + NNODES + 1;                    // 50000
    int* eidx   = cursor + NNODES;                       // 800000 (+pad)
    int2* ss    = (int2*)(eidx + NEDGES + 64);           // 800000 int2 (+pad)
    int* bsum   = (int*)(ss + NEDGES + 64);              // 256

    hipMemsetAsync(deg, 0, NNODES * sizeof(int), stream);
    prep_hist<<<3 + (NEDGES + 255) / 256, 256, 0, stream>>>(We, W1, W2, Wep, W1p,
                                                            W2p, ei, deg);
    scan_partial<<<SCAN_BLOCKS, 256, 0, stream>>>(deg, bsum);
    scan_write<<<SCAN_BLOCKS, 256, 0, stream>>>(deg, bsum, start, cursor);
    fill_kernel<<<(NEDGES + 255) / 256, 256, 0, stream>>>(ei, cursor, eidx, ss);
    int nwaves = (NNODES + NBW - 1) / NBW;               // 12500
    int nblocks = (nwaves + WPB - 1) / WPB;              // 3125
    fused_edge_aggr<<<nblocks, 256, 0, stream>>>(ea, eidx, ss, start, x,
                                                 Wep, be, eps, h);
    int nwaves2 = (NNODES + NPW - 1) / NPW;              // 3125
    int nblocks2 = (nwaves2 + 3) / 4;                    // 782
    node_mfma<<<nblocks2, 256, 0, stream>>>(h, W1p, b1, W2p, b2, out);
}

// Round 14
// 277.179 us; speedup vs baseline: 1.1750x; 1.1750x over previous
//
#include <hip/hip_runtime.h>

#define NNODES 50000
#define NEDGES 800000
#define NF 96
#define NF4 24              // float4 per f32 row
#define NBW 4               // nodes per wave (fused): 12500 waves total
#define WPB 4               // waves per block (256 threads)
#define ACC_STRIDE 97       // Acc row stride (floats)
#define NPW 16              // nodes per wave (node MLP)
#define TSTRIDE 100         // h1 transpose tile stride (floats, 16B-aligned)

typedef short bf16x8 __attribute__((ext_vector_type(8)));
typedef float f32x4 __attribute__((ext_vector_type(4)));

__device__ inline unsigned pk_bf16(float a, float b) {
    union { __bf16 h[2]; unsigned u; } q;
    q.h[0] = (__bf16)a; q.h[1] = (__bf16)b;
    return q.u;
}
__device__ inline unsigned short bf16_1(float a) {
    union { __bf16 h; unsigned short u; } q;
    q.h = (__bf16)a;
    return q.u;
}
__device__ inline bf16x8 cvt8(float4 a, float4 b) {
    union { unsigned u[4]; bf16x8 v; } q;
    q.u[0] = pk_bf16(a.x, a.y); q.u[1] = pk_bf16(a.z, a.w);
    q.u[2] = pk_bf16(b.x, b.y); q.u[3] = pk_bf16(b.z, b.w);
    return q.v;
}
__device__ inline int imin(int a, int b) { return a < b ? a : b; }

// ---------------------------------------------------------------------------
// prep: blocks 0/1/2 pack We/W1/W2 into MFMA B-fragment order (bf16);
// remaining blocks do the dst histogram.
// ---------------------------------------------------------------------------
__global__ __launch_bounds__(256) void prep_hist(
    const float* __restrict__ We, const float* __restrict__ W1,
    const float* __restrict__ W2, unsigned short* __restrict__ Wep,
    unsigned short* __restrict__ W1p, unsigned short* __restrict__ W2p,
    const int* __restrict__ ei, int* __restrict__ deg) {
    int b = blockIdx.x;
    if (b < 3) {
        const float* S = (b == 0) ? We : (b == 1) ? W1 : W2;
        unsigned short* D = (b == 0) ? Wep : (b == 1) ? W1p : W2p;
        for (int i = threadIdx.x; i < 18 * 64 * 8; i += blockDim.x) {
            int f = i >> 9, rem = i & 511;
            int l = rem >> 3, j = rem & 7;
            int ot = f / 3, kb = f % 3;
            int o = ot * 16 + (l & 15);
            int k = kb * 32 + ((l >> 4) << 3) + j;
            D[i] = bf16_1(S[o * NF + k]);
        }
    } else {
        int e = (b - 3) * 256 + threadIdx.x;
        if (e < NEDGES) atomicAdd(&deg[ei[NEDGES + e]], 1);
    }
}

// ---------------------------------------------------------------------------
// 2-kernel scan (partial sums; write does local scan of partials) + fill
// ---------------------------------------------------------------------------
#define SCAN_BLOCKS 196  // ceil(50000 / 256)

__global__ __launch_bounds__(256) void scan_partial(const int* __restrict__ deg,
                                                    int* __restrict__ bsum) {
    __shared__ int red[256];
    int t = threadIdx.x;
    int i = blockIdx.x * 256 + t;
    red[t] = (i < NNODES) ? deg[i] : 0;
    __syncthreads();
    for (int off = 128; off; off >>= 1) {
        if (t < off) red[t] += red[t + off];
        __syncthreads();
    }
    if (t == 0) bsum[blockIdx.x] = red[0];
}

__global__ __launch_bounds__(256) void scan_write(const int* __restrict__ deg,
                                                  const int* __restrict__ bsum,
                                                  int* __restrict__ start,
                                                  int* __restrict__ cursor) {
    __shared__ int sb[256];
    __shared__ int s[256];
    int t = threadIdx.x;
    sb[t] = (t < SCAN_BLOCKS) ? bsum[t] : 0;
    __syncthreads();
    for (int off = 1; off < 256; off <<= 1) {
        int v = (t >= off) ? sb[t - off] : 0;
        __syncthreads();
        sb[t] += v;
        __syncthreads();
    }
    int bbase = (blockIdx.x == 0) ? 0 : sb[blockIdx.x - 1];

    int i = blockIdx.x * 256 + t;
    int d = (i < NNODES) ? deg[i] : 0;
    s[t] = d;
    __syncthreads();
    for (int off = 1; off < 256; off <<= 1) {
        int v = (t >= off) ? s[t - off] : 0;
        __syncthreads();
        s[t] += v;
        __syncthreads();
    }
    int excl = ((t == 0) ? 0 : s[t - 1]) + bbase;
    if (i < NNODES) {
        start[i] = excl;
        cursor[i] = excl;
        if (i == NNODES - 1) start[NNODES] = excl + d;
    }
}

// fill: eidx[p] = edge id; ss[p] = (src, dst) packed
__global__ void fill_kernel(const int* __restrict__ ei, int* __restrict__ cursor,
                            int* __restrict__ eidx, int2* __restrict__ ss) {
    int e = blockIdx.x * blockDim.x + threadIdx.x;
    if (e < NEDGES) {
        int d = ei[NEDGES + e];
        int p = atomicAdd(&cursor[d], 1);
        eidx[p] = e;
        ss[p] = make_int2(ei[e], d);
    }
}

// ---------------------------------------------------------------------------
// Wave-autonomous fused edge-GEMM + segment-sum (R12 structure).
// R14 delta: loop-swapped epilogue — one divergent flush region per segment
// boundary (4 total) covering all 6 ot atomics, instead of 4 checks x 6 ot.
// ---------------------------------------------------------------------------
__global__ __launch_bounds__(256) void fused_edge_aggr(
    const float* __restrict__ attr, const int* __restrict__ eidx,
    const int2* __restrict__ ss_g, const int* __restrict__ start,
    const float* __restrict__ x, const unsigned short* __restrict__ Wpack,
    const float* __restrict__ be, const float* __restrict__ epsp,
    float* __restrict__ h) {
    __shared__ short Wlds[18 * 64 * 8];             // 18,432 B
    __shared__ float Acc[WPB][NBW][ACC_STRIDE];     //  6,208 B

    const int t = threadIdx.x;
    {
        const uint4* wsrc = reinterpret_cast<const uint4*>(Wpack);
        uint4* wdst = reinterpret_cast<uint4*>(Wlds);
        for (int i = t; i < 18 * 64; i += 256) wdst[i] = wsrc[i];
        float* accf = &Acc[0][0][0];
        for (int i = t; i < WPB * NBW * ACC_STRIDE; i += 256) accf[i] = 0.f;
    }
    __syncthreads();

    const int w = t >> 6;
    const int lane = t & 63;
    const int l15 = lane & 15, l4 = lane >> 4;
    const int n0w = (blockIdx.x * WPB + w) * NBW;
    if (n0w >= NNODES) return;
    const int s0 = start[n0w], s1 = start[n0w + NBW];
    float* AccW = &Acc[w][0][0];

    float bias[6];
#pragma unroll
    for (int ot = 0; ot < 6; ++ot) bias[ot] = be[ot * 16 + l15];

    const float4* a4 = reinterpret_cast<const float4*>(attr);
    const int nt = (s1 - s0 + 15) >> 4;

    if (nt > 0) {
        const int smax = s1 - 1;

        // ---- prologue: tile 0 data (attr + xe) + tile 1 indices ----
        float4 a_cur[6];
        float xe_cur[4][6];
        int2 ss_cur[4], ss_nxt[4];
        int ev_nxt;
        {
            int ev0 = eidx[imin(s0 + l15, smax)];
            const float4* ar = a4 + (size_t)ev0 * NF4 + l4 * 2;
            a_cur[0] = ar[0];  a_cur[1] = ar[1];
            a_cur[2] = ar[8];  a_cur[3] = ar[9];
            a_cur[4] = ar[16]; a_cur[5] = ar[17];
            ev_nxt = eidx[imin(s0 + 16 + l15, smax)];
#pragma unroll
            for (int r = 0; r < 4; ++r) {
                ss_cur[r] = ss_g[imin(s0 + l4 * 4 + r, smax)];
                ss_nxt[r] = ss_g[imin(s0 + 16 + l4 * 4 + r, smax)];
            }
#pragma unroll
            for (int r = 0; r < 4; ++r) {
                const float* xr = x + (size_t)ss_cur[r].x * NF + l15;
#pragma unroll
                for (int ot = 0; ot < 6; ++ot) xe_cur[r][ot] = xr[ot * 16];
            }
        }

        for (int tt = 0; tt < nt; ++tt) {
            const int base = s0 + 16 * tt;

            // ---- 1. consume current attr regs ----
            bf16x8 af[3];
            af[0] = cvt8(a_cur[0], a_cur[1]);
            af[1] = cvt8(a_cur[2], a_cur[3]);
            af[2] = cvt8(a_cur[4], a_cur[5]);

            // ---- 2. reissue attr loads for tile tt+1 (unconditional) ----
            {
                const float4* ar = a4 + (size_t)ev_nxt * NF4 + l4 * 2;
                a_cur[0] = ar[0];  a_cur[1] = ar[1];
                a_cur[2] = ar[8];  a_cur[3] = ar[9];
                a_cur[4] = ar[16]; a_cur[5] = ar[17];
            }

            // ---- 3. eidx for tile tt+2 ----
            ev_nxt = eidx[imin(base + 32 + l15, smax)];

            // ---- 4. current masks; prefetch xe for tile tt+1 (ss_nxt) ----
            int m[4];
#pragma unroll
            for (int r = 0; r < 4; ++r)
                m[r] = ((base + l4 * 4 + r) < s1) ? (ss_cur[r].y - n0w) : -1;

            float xe_nxt[4][6];
#pragma unroll
            for (int r = 0; r < 4; ++r) {
                const float* xr = x + (size_t)ss_nxt[r].x * NF + l15;
#pragma unroll
                for (int ot = 0; ot < 6; ++ot) xe_nxt[r][ot] = xr[ot * 16];
            }

            // ---- 5. rotate index state; load tile tt+2 indices ----
#pragma unroll
            for (int r = 0; r < 4; ++r) ss_cur[r] = ss_nxt[r];
#pragma unroll
            for (int r = 0; r < 4; ++r)
                ss_nxt[r] = ss_g[imin(base + 32 + l4 * 4 + r, smax)];

            // ---- 6. 18 MFMA: D[e][o] ----
            f32x4 acc[6];
#pragma unroll
            for (int ot = 0; ot < 6; ++ot) {
                f32x4 c = {bias[ot], bias[ot], bias[ot], bias[ot]};
#pragma unroll
                for (int kb = 0; kb < 3; ++kb) {
                    bf16x8 bf = *reinterpret_cast<const bf16x8*>(
                        &Wlds[((ot * 3 + kb) * 64 + lane) * 8]);
                    c = __builtin_amdgcn_mfma_f32_16x16x32_bf16(af[kb], bf, c,
                                                                0, 0, 0);
                }
                acc[ot] = c;
            }

            // ---- 7. epilogue (loop-swapped): relu all, then per-boundary
            //         flush of all 6 ot under ONE divergent region ----
            float v0s[6], v1s[6], v2s[6], v3s[6];
#pragma unroll
            for (int ot = 0; ot < 6; ++ot) {
                v0s[ot] = fmaxf(acc[ot][0] + xe_cur[0][ot], 0.f);
                v1s[ot] = fmaxf(acc[ot][1] + xe_cur[1][ot], 0.f);
                v2s[ot] = fmaxf(acc[ot][2] + xe_cur[2][ot], 0.f);
                v3s[ot] = fmaxf(acc[ot][3] + xe_cur[3][ot], 0.f);
            }
            float run[6];
#pragma unroll
            for (int ot = 0; ot < 6; ++ot) run[ot] = v0s[ot];
            if (m[1] != m[0]) {
                if (m[0] >= 0) {
                    float* arow = &AccW[m[0] * ACC_STRIDE + l15];
#pragma unroll
                    for (int ot = 0; ot < 6; ++ot)
                        atomicAdd(arow + ot * 16, run[ot]);
                }
#pragma unroll
                for (int ot = 0; ot < 6; ++ot) run[ot] = 0.f;
            }
#pragma unroll
            for (int ot = 0; ot < 6; ++ot) run[ot] += v1s[ot];
            if (m[2] != m[1]) {
                if (m[1] >= 0) {
                    float* arow = &AccW[m[1] * ACC_STRIDE + l15];
#pragma unroll
                    for (int ot = 0; ot < 6; ++ot)
                        atomicAdd(arow + ot * 16, run[ot]);
                }
#pragma unroll
                for (int ot = 0; ot < 6; ++ot) run[ot] = 0.f;
            }
#pragma unroll
            for (int ot = 0; ot < 6; ++ot) run[ot] += v2s[ot];
            if (m[3] != m[2]) {
                if (m[2] >= 0) {
                    float* arow = &AccW[m[2] * ACC_STRIDE + l15];
#pragma unroll
                    for (int ot = 0; ot < 6; ++ot)
                        atomicAdd(arow + ot * 16, run[ot]);
                }
#pragma unroll
                for (int ot = 0; ot < 6; ++ot) run[ot] = 0.f;
            }
#pragma unroll
            for (int ot = 0; ot < 6; ++ot) run[ot] += v3s[ot];
            if (m[3] >= 0) {
                float* arow = &AccW[m[3] * ACC_STRIDE + l15];
#pragma unroll
                for (int ot = 0; ot < 6; ++ot)
                    atomicAdd(arow + ot * 16, run[ot]);
            }

            // ---- 8. rotate xe ----
#pragma unroll
            for (int r = 0; r < 4; ++r)
#pragma unroll
                for (int ot = 0; ot < 6; ++ot) xe_cur[r][ot] = xe_nxt[r][ot];
        }
    }

    // ---- drain this wave's ds_adds, then write h (wave-private) ----
    asm volatile("s_waitcnt lgkmcnt(0)" ::: "memory");
    __builtin_amdgcn_sched_barrier(0);
    const float ep = 1.0f + *epsp;
#pragma unroll
    for (int i = 0; i < NBW * NF / 64; ++i) {  // 6
        int item = lane + 64 * i;
        int n = item / NF, f = item % NF;
        float a = AccW[n * ACC_STRIDE + f];
        size_t g = (size_t)(n0w + n) * NF + f;
        h[g] = fmaf(ep, x[g], a);
    }
}

// ---------------------------------------------------------------------------
// Node MLP via bf16 MFMA. Wave owns NPW=16 nodes (contiguous, dense rows).
// ---------------------------------------------------------------------------
__global__ __launch_bounds__(256) void node_mfma(
    const float* __restrict__ h, const unsigned short* __restrict__ W1p,
    const float* __restrict__ b1, const unsigned short* __restrict__ W2p,
    const float* __restrict__ b2, float* __restrict__ out) {
    __shared__ short W1lds[18 * 64 * 8];          // 18,432 B
    __shared__ short W2lds[18 * 64 * 8];          // 18,432 B
    __shared__ float T[4][NPW][TSTRIDE];          // 25,600 B

    const int t = threadIdx.x;
    {
        const uint4* s1v = reinterpret_cast<const uint4*>(W1p);
        const uint4* s2v = reinterpret_cast<const uint4*>(W2p);
        uint4* d1 = reinterpret_cast<uint4*>(W1lds);
        uint4* d2 = reinterpret_cast<uint4*>(W2lds);
        for (int i = t; i < 18 * 64; i += 256) { d1[i] = s1v[i]; d2[i] = s2v[i]; }
    }
    __syncthreads();

    const int w = t >> 6;
    const int lane = t & 63;
    const int l15 = lane & 15, l4 = lane >> 4;
    const int n0 = (blockIdx.x * 4 + w) * NPW;
    if (n0 >= NNODES) return;

    const float4* hrow = reinterpret_cast<const float4*>(h + (size_t)(n0 + l15) * NF);
    bf16x8 af[3];
#pragma unroll
    for (int kb = 0; kb < 3; ++kb)
        af[kb] = cvt8(hrow[kb * 8 + l4 * 2], hrow[kb * 8 + l4 * 2 + 1]);

    float* Tw = &T[w][0][0];
#pragma unroll
    for (int ot = 0; ot < 6; ++ot) {
        float b = b1[ot * 16 + l15];
        f32x4 c = {b, b, b, b};
#pragma unroll
        for (int kb = 0; kb < 3; ++kb) {
            bf16x8 bf = *reinterpret_cast<const bf16x8*>(
                &W1lds[((ot * 3 + kb) * 64 + lane) * 8]);
            c = __builtin_amdgcn_mfma_f32_16x16x32_bf16(af[kb], bf, c, 0, 0, 0);
        }
#pragma unroll
        for (int r = 0; r < 4; ++r)
            Tw[(l4 * 4 + r) * TSTRIDE + ot * 16 + l15] = fmaxf(c[r], 0.f);
    }

    asm volatile("s_waitcnt lgkmcnt(0)" ::: "memory");
    __builtin_amdgcn_sched_barrier(0);

    bf16x8 af2[3];
#pragma unroll
    for (int kb = 0; kb < 3; ++kb) {
        const float4* tr = reinterpret_cast<const float4*>(
            &Tw[l15 * TSTRIDE + kb * 32 + l4 * 8]);
        af2[kb] = cvt8(tr[0], tr[1]);
    }
#pragma unroll
    for (int ot = 0; ot < 6; ++ot) {
        float b = b2[ot * 16 + l15];
        f32x4 c = {b, b, b, b};
#pragma unroll
        for (int kb = 0; kb < 3; ++kb) {
            bf16x8 bf = *reinterpret_cast<const bf16x8*>(
                &W2lds[((ot * 3 + kb) * 64 + lane) * 8]);
            c = __builtin_amdgcn_mfma_f32_16x16x32_bf16(af2[kb], bf, c, 0, 0, 0);
        }
#pragma unroll
        for (int r = 0; r < 4; ++r)
            out[(size_t)(n0 + l4 * 4 + r) * NF + ot * 16 + l15] = c[r];
    }
}

// ---------------------------------------------------------------------------
extern "C" void kernel_launch(void* const* d_in, const int* in_sizes, int n_in,
                              void* d_out, int out_size, void* d_ws, size_t ws_size,
                              hipStream_t stream) {
    const float* x   = (const float*)d_in[0];
    const int*   ei  = (const int*)d_in[1];
    const float* ea  = (const float*)d_in[2];
    const float* We  = (const float*)d_in[3];
    const float* be  = (const float*)d_in[4];
    const float* eps = (const float*)d_in[5];
    const float* W1  = (const float*)d_in[6];
    const float* b1  = (const float*)d_in[7];
    const float* W2  = (const float*)d_in[8];
    const float* b2  = (const float*)d_in[9];
    float* out = (float*)d_out;

    // ws layout
    float* h    = (float*)d_ws;                          // 50000*96 f (19.2 MB)
    unsigned short* Wep = (unsigned short*)(h + (size_t)NNODES * NF);  // 9216
    unsigned short* W1p = Wep + 18 * 64 * 8;             // 9216
    unsigned short* W2p = W1p + 18 * 64 * 8;             // 9216
    int* deg    = (int*)(W2p + 18 * 64 * 8);             // 50000
    int* start  = deg + NNODES;                          // 50001
    int* cursor = start + NNODES + 1;                    // 50000
    int* eidx   = cursor + NNODES;                       // 800000 (+pad)
    int2* ss    = (int2*)(eidx + NEDGES + 64);           // 800000 int2 (+pad)
    int* bsum   = (int*)(ss + NEDGES + 64);              // 256

    hipMemsetAsync(deg, 0, NNODES * sizeof(int), stream);
    prep_hist<<<3 + (NEDGES + 255) / 256, 256, 0, stream>>>(We, W1, W2, Wep, W1p,
                                                            W2p, ei, deg);
    scan_partial<<<SCAN_BLOCKS, 256, 0, stream>>>(deg, bsum);
    scan_write<<<SCAN_BLOCKS, 256, 0, stream>>>(deg, bsum, start, cursor);
    fill_kernel<<<(NEDGES + 255) / 256, 256, 0, stream>>>(ei, cursor, eidx, ss);
    int nwaves = (NNODES + NBW - 1) / NBW;               // 12500
    int nblocks = (nwaves + WPB - 1) / WPB;              // 3125
    fused_edge_aggr<<<nblocks, 256, 0, stream>>>(ea, eidx, ss, start, x,
                                                 Wep, be, eps, h);
    int nwaves2 = (NNODES + NPW - 1) / NPW;              // 3125
    int nblocks2 = (nwaves2 + 3) / 4;                    // 782
    node_mfma<<<nblocks2, 256, 0, stream>>>(h, W1p, b1, W2p, b2, out);
}

// Round 15
// 273.388 us; speedup vs baseline: 1.1913x; 1.0139x over previous
//
#include <hip/hip_runtime.h>

#define NNODES 50000
#define NEDGES 800000
#define NF 96
#define NF4 24              // float4 per f32 row
#define NBW 4               // nodes per wave (fused): 12500 waves total
#define WPB 4               // waves per block (256 threads); block owns 16 nodes
#define ACC_STRIDE 100      // Acc/T/Ht row stride (floats, 400B, 16B-aligned)

typedef short bf16x8 __attribute__((ext_vector_type(8)));
typedef float f32x4 __attribute__((ext_vector_type(4)));

__device__ inline unsigned pk_bf16(float a, float b) {
    union { __bf16 h[2]; unsigned u; } q;
    q.h[0] = (__bf16)a; q.h[1] = (__bf16)b;
    return q.u;
}
__device__ inline unsigned short bf16_1(float a) {
    union { __bf16 h; unsigned short u; } q;
    q.h = (__bf16)a;
    return q.u;
}
__device__ inline bf16x8 cvt8(float4 a, float4 b) {
    union { unsigned u[4]; bf16x8 v; } q;
    q.u[0] = pk_bf16(a.x, a.y); q.u[1] = pk_bf16(a.z, a.w);
    q.u[2] = pk_bf16(b.x, b.y); q.u[3] = pk_bf16(b.z, b.w);
    return q.v;
}
__device__ inline int imin(int a, int b) { return a < b ? a : b; }

// ---------------------------------------------------------------------------
// prep: blocks 0/1/2 pack We/W1/W2 into MFMA B-fragment order (bf16);
// remaining blocks do the dst histogram.
// ---------------------------------------------------------------------------
__global__ __launch_bounds__(256) void prep_hist(
    const float* __restrict__ We, const float* __restrict__ W1,
    const float* __restrict__ W2, unsigned short* __restrict__ Wep,
    unsigned short* __restrict__ W1p, unsigned short* __restrict__ W2p,
    const int* __restrict__ ei, int* __restrict__ deg) {
    int b = blockIdx.x;
    if (b < 3) {
        const float* S = (b == 0) ? We : (b == 1) ? W1 : W2;
        unsigned short* D = (b == 0) ? Wep : (b == 1) ? W1p : W2p;
        for (int i = threadIdx.x; i < 18 * 64 * 8; i += blockDim.x) {
            int f = i >> 9, rem = i & 511;
            int l = rem >> 3, j = rem & 7;
            int ot = f / 3, kb = f % 3;
            int o = ot * 16 + (l & 15);
            int k = kb * 32 + ((l >> 4) << 3) + j;
            D[i] = bf16_1(S[o * NF + k]);
        }
    } else {
        int e = (b - 3) * 256 + threadIdx.x;
        if (e < NEDGES) atomicAdd(&deg[ei[NEDGES + e]], 1);
    }
}

// ---------------------------------------------------------------------------
// 2-kernel scan (partial sums; write does local scan of partials) + fill
// ---------------------------------------------------------------------------
#define SCAN_BLOCKS 196  // ceil(50000 / 256)

__global__ __launch_bounds__(256) void scan_partial(const int* __restrict__ deg,
                                                    int* __restrict__ bsum) {
    __shared__ int red[256];
    int t = threadIdx.x;
    int i = blockIdx.x * 256 + t;
    red[t] = (i < NNODES) ? deg[i] : 0;
    __syncthreads();
    for (int off = 128; off; off >>= 1) {
        if (t < off) red[t] += red[t + off];
        __syncthreads();
    }
    if (t == 0) bsum[blockIdx.x] = red[0];
}

__global__ __launch_bounds__(256) void scan_write(const int* __restrict__ deg,
                                                  const int* __restrict__ bsum,
                                                  int* __restrict__ start,
                                                  int* __restrict__ cursor) {
    __shared__ int sb[256];
    __shared__ int s[256];
    int t = threadIdx.x;
    sb[t] = (t < SCAN_BLOCKS) ? bsum[t] : 0;
    __syncthreads();
    for (int off = 1; off < 256; off <<= 1) {
        int v = (t >= off) ? sb[t - off] : 0;
        __syncthreads();
        sb[t] += v;
        __syncthreads();
    }
    int bbase = (blockIdx.x == 0) ? 0 : sb[blockIdx.x - 1];

    int i = blockIdx.x * 256 + t;
    int d = (i < NNODES) ? deg[i] : 0;
    s[t] = d;
    __syncthreads();
    for (int off = 1; off < 256; off <<= 1) {
        int v = (t >= off) ? s[t - off] : 0;
        __syncthreads();
        s[t] += v;
        __syncthreads();
    }
    int excl = ((t == 0) ? 0 : s[t - 1]) + bbase;
    if (i < NNODES) {
        start[i] = excl;
        cursor[i] = excl;
        if (i == NNODES - 1) start[NNODES] = excl + d;
    }
}

// fill: eidx[p] = edge id; ss[p] = (src, dst) packed
__global__ void fill_kernel(const int* __restrict__ ei, int* __restrict__ cursor,
                            int* __restrict__ eidx, int2* __restrict__ ss) {
    int e = blockIdx.x * blockDim.x + threadIdx.x;
    if (e < NEDGES) {
        int d = ei[NEDGES + e];
        int p = atomicAdd(&cursor[d], 1);
        eidx[p] = e;
        ss[p] = make_int2(ei[e], d);
    }
}

// ---------------------------------------------------------------------------
// Fully fused: edge-GEMM + segment-sum (R12 pipeline) + tail node-MLP.
// Block owns 16 contiguous nodes (wave w: nodes w*4..w*4+3).
// Tail: h -> Ht LDS, barrier, 4 waves split the 2-layer MLP (ot-slices),
// T aliases the dead Acc region. out written directly; no h round-trip.
// ---------------------------------------------------------------------------
__global__ __launch_bounds__(256) void fused_all(
    const float* __restrict__ attr, const int* __restrict__ eidx,
    const int2* __restrict__ ss_g, const int* __restrict__ start,
    const float* __restrict__ x, const unsigned short* __restrict__ Wpack,
    const float* __restrict__ be, const float* __restrict__ epsp,
    const unsigned short* __restrict__ W1p, const float* __restrict__ b1,
    const unsigned short* __restrict__ W2p, const float* __restrict__ b2,
    float* __restrict__ out) {
    __shared__ short Wlds[18 * 64 * 8];               // 18,432 B
    __shared__ float AccT[WPB * NBW * ACC_STRIDE];    //  6,400 B (Acc -> T)
    __shared__ float Ht[16][ACC_STRIDE];              //  6,400 B

    const int t = threadIdx.x;
    {
        const uint4* wsrc = reinterpret_cast<const uint4*>(Wpack);
        uint4* wdst = reinterpret_cast<uint4*>(Wlds);
        for (int i = t; i < 18 * 64; i += 256) wdst[i] = wsrc[i];
        for (int i = t; i < WPB * NBW * ACC_STRIDE; i += 256) AccT[i] = 0.f;
    }
    __syncthreads();

    const int w = t >> 6;
    const int lane = t & 63;
    const int l15 = lane & 15, l4 = lane >> 4;
    const int n0w = (blockIdx.x * WPB + w) * NBW;      // grid exact: < NNODES
    const int s0 = start[n0w], s1 = start[n0w + NBW];
    float* AccW = &AccT[w * NBW * ACC_STRIDE];

    float bias[6];
#pragma unroll
    for (int ot = 0; ot < 6; ++ot) bias[ot] = be[ot * 16 + l15];

    const float4* a4 = reinterpret_cast<const float4*>(attr);
    const int nt = (s1 - s0 + 15) >> 4;

    if (nt > 0) {
        const int smax = s1 - 1;

        // ---- prologue: tile 0 data (attr + xe) + tile 1 indices ----
        float4 a_cur[6];
        float xe_cur[4][6];
        int2 ss_cur[4], ss_nxt[4];
        int ev_nxt;
        {
            int ev0 = eidx[imin(s0 + l15, smax)];
            const float4* ar = a4 + (size_t)ev0 * NF4 + l4 * 2;
            a_cur[0] = ar[0];  a_cur[1] = ar[1];
            a_cur[2] = ar[8];  a_cur[3] = ar[9];
            a_cur[4] = ar[16]; a_cur[5] = ar[17];
            ev_nxt = eidx[imin(s0 + 16 + l15, smax)];
#pragma unroll
            for (int r = 0; r < 4; ++r) {
                ss_cur[r] = ss_g[imin(s0 + l4 * 4 + r, smax)];
                ss_nxt[r] = ss_g[imin(s0 + 16 + l4 * 4 + r, smax)];
            }
#pragma unroll
            for (int r = 0; r < 4; ++r) {
                const float* xr = x + (size_t)ss_cur[r].x * NF + l15;
#pragma unroll
                for (int ot = 0; ot < 6; ++ot) xe_cur[r][ot] = xr[ot * 16];
            }
        }

        for (int tt = 0; tt < nt; ++tt) {
            const int base = s0 + 16 * tt;

            bf16x8 af[3];
            af[0] = cvt8(a_cur[0], a_cur[1]);
            af[1] = cvt8(a_cur[2], a_cur[3]);
            af[2] = cvt8(a_cur[4], a_cur[5]);

            {
                const float4* ar = a4 + (size_t)ev_nxt * NF4 + l4 * 2;
                a_cur[0] = ar[0];  a_cur[1] = ar[1];
                a_cur[2] = ar[8];  a_cur[3] = ar[9];
                a_cur[4] = ar[16]; a_cur[5] = ar[17];
            }
            ev_nxt = eidx[imin(base + 32 + l15, smax)];

            int m[4];
#pragma unroll
            for (int r = 0; r < 4; ++r)
                m[r] = ((base + l4 * 4 + r) < s1) ? (ss_cur[r].y - n0w) : -1;

            float xe_nxt[4][6];
#pragma unroll
            for (int r = 0; r < 4; ++r) {
                const float* xr = x + (size_t)ss_nxt[r].x * NF + l15;
#pragma unroll
                for (int ot = 0; ot < 6; ++ot) xe_nxt[r][ot] = xr[ot * 16];
            }

#pragma unroll
            for (int r = 0; r < 4; ++r) ss_cur[r] = ss_nxt[r];
#pragma unroll
            for (int r = 0; r < 4; ++r)
                ss_nxt[r] = ss_g[imin(base + 32 + l4 * 4 + r, smax)];

            f32x4 acc[6];
#pragma unroll
            for (int ot = 0; ot < 6; ++ot) {
                f32x4 c = {bias[ot], bias[ot], bias[ot], bias[ot]};
#pragma unroll
                for (int kb = 0; kb < 3; ++kb) {
                    bf16x8 bf = *reinterpret_cast<const bf16x8*>(
                        &Wlds[((ot * 3 + kb) * 64 + lane) * 8]);
                    c = __builtin_amdgcn_mfma_f32_16x16x32_bf16(af[kb], bf, c,
                                                                0, 0, 0);
                }
                acc[ot] = c;
            }

            const bool c1 = (m[1] == m[0]);
            const bool c2 = (m[2] == m[1]);
            const bool c3 = (m[3] == m[2]);
#pragma unroll
            for (int ot = 0; ot < 6; ++ot) {
                const int o = ot * 16 + l15;
                float v0 = fmaxf(acc[ot][0] + xe_cur[0][ot], 0.f);
                float v1 = fmaxf(acc[ot][1] + xe_cur[1][ot], 0.f);
                float v2 = fmaxf(acc[ot][2] + xe_cur[2][ot], 0.f);
                float v3 = fmaxf(acc[ot][3] + xe_cur[3][ot], 0.f);
                float run = v0;
                if (!c1) {
                    if (m[0] >= 0) atomicAdd(&AccW[m[0] * ACC_STRIDE + o], run);
                    run = 0.f;
                }
                run += v1;
                if (!c2) {
                    if (m[1] >= 0) atomicAdd(&AccW[m[1] * ACC_STRIDE + o], run);
                    run = 0.f;
                }
                run += v2;
                if (!c3) {
                    if (m[2] >= 0) atomicAdd(&AccW[m[2] * ACC_STRIDE + o], run);
                    run = 0.f;
                }
                run += v3;
                if (m[3] >= 0) atomicAdd(&AccW[m[3] * ACC_STRIDE + o], run);
            }

#pragma unroll
            for (int r = 0; r < 4; ++r)
#pragma unroll
                for (int ot = 0; ot < 6; ++ot) xe_cur[r][ot] = xe_nxt[r][ot];
        }
    }

    // ---- drain this wave's ds_adds; build Ht = (1+eps)x + Acc ----
    asm volatile("s_waitcnt lgkmcnt(0)" ::: "memory");
    __builtin_amdgcn_sched_barrier(0);
    const float ep = 1.0f + *epsp;
#pragma unroll
    for (int i = 0; i < NBW * NF / 64; ++i) {  // 6
        int item = lane + 64 * i;
        int n = item / NF, f = item % NF;
        Ht[w * NBW + n][f] =
            fmaf(ep, x[(size_t)(n0w + n) * NF + f], AccW[n * ACC_STRIDE + f]);
    }
    __syncthreads();   // Ht complete; Acc dead -> AccT becomes T

    // ---- tail MLP for the block's 16 nodes; waves split ot-slices ----
    const int nb0 = blockIdx.x * (WPB * NBW);

    bf16x8 af1[3];
#pragma unroll
    for (int kb = 0; kb < 3; ++kb) {
        const float4* tr = reinterpret_cast<const float4*>(
            &Ht[l15][kb * 32 + l4 * 8]);
        af1[kb] = cvt8(tr[0], tr[1]);
    }
    for (int ot = w; ot < 6; ot += WPB) {
        float b = b1[ot * 16 + l15];
        f32x4 c = {b, b, b, b};
#pragma unroll
        for (int kb = 0; kb < 3; ++kb) {
            bf16x8 bf = *reinterpret_cast<const bf16x8*>(
                W1p + ((ot * 3 + kb) * 64 + lane) * 8);
            c = __builtin_amdgcn_mfma_f32_16x16x32_bf16(af1[kb], bf, c, 0, 0, 0);
        }
#pragma unroll
        for (int r = 0; r < 4; ++r)
            AccT[(l4 * 4 + r) * ACC_STRIDE + ot * 16 + l15] = fmaxf(c[r], 0.f);
    }
    __syncthreads();   // T complete

    bf16x8 af2[3];
#pragma unroll
    for (int kb = 0; kb < 3; ++kb) {
        const float4* tr = reinterpret_cast<const float4*>(
            &AccT[l15 * ACC_STRIDE + kb * 32 + l4 * 8]);
        af2[kb] = cvt8(tr[0], tr[1]);
    }
    for (int ot = w; ot < 6; ot += WPB) {
        float b = b2[ot * 16 + l15];
        f32x4 c = {b, b, b, b};
#pragma unroll
        for (int kb = 0; kb < 3; ++kb) {
            bf16x8 bf = *reinterpret_cast<const bf16x8*>(
                W2p + ((ot * 3 + kb) * 64 + lane) * 8);
            c = __builtin_amdgcn_mfma_f32_16x16x32_bf16(af2[kb], bf, c, 0, 0, 0);
        }
#pragma unroll
        for (int r = 0; r < 4; ++r)
            out[(size_t)(nb0 + l4 * 4 + r) * NF + ot * 16 + l15] = c[r];
    }
}

// ---------------------------------------------------------------------------
extern "C" void kernel_launch(void* const* d_in, const int* in_sizes, int n_in,
                              void* d_out, int out_size, void* d_ws, size_t ws_size,
                              hipStream_t stream) {
    const float* x   = (const float*)d_in[0];
    const int*   ei  = (const int*)d_in[1];
    const float* ea  = (const float*)d_in[2];
    const float* We  = (const float*)d_in[3];
    const float* be  = (const float*)d_in[4];
    const float* eps = (const float*)d_in[5];
    const float* W1  = (const float*)d_in[6];
    const float* b1  = (const float*)d_in[7];
    const float* W2  = (const float*)d_in[8];
    const float* b2  = (const float*)d_in[9];
    float* out = (float*)d_out;

    // ws layout (h eliminated)
    unsigned short* Wep = (unsigned short*)d_ws;         // 9216 bf16
    unsigned short* W1p = Wep + 18 * 64 * 8;             // 9216
    unsigned short* W2p = W1p + 18 * 64 * 8;             // 9216
    int* deg    = (int*)(W2p + 18 * 64 * 8);             // 50000
    int* start  = deg + NNODES;                          // 50001
    int* cursor = start + NNODES + 1;                    // 50000
    int* eidx   = cursor + NNODES;                       // 800000 (+pad)
    int2* ss    = (int2*)(eidx + NEDGES + 64);           // 800000 int2 (+pad)
    int* bsum   = (int*)(ss + NEDGES + 64);              // 256

    hipMemsetAsync(deg, 0, NNODES * sizeof(int), stream);
    prep_hist<<<3 + (NEDGES + 255) / 256, 256, 0, stream>>>(We, W1, W2, Wep, W1p,
                                                            W2p, ei, deg);
    scan_partial<<<SCAN_BLOCKS, 256, 0, stream>>>(deg, bsum);
    scan_write<<<SCAN_BLOCKS, 256, 0, stream>>>(deg, bsum, start, cursor);
    fill_kernel<<<(NEDGES + 255) / 256, 256, 0, stream>>>(ei, cursor, eidx, ss);
    int nblocks = NNODES / (WPB * NBW);                  // 3125 exact
    fused_all<<<nblocks, 256, 0, stream>>>(ea, eidx, ss, start, x, Wep, be, eps,
                                           W1p, b1, W2p, b2, out);
}